// Round 3
// baseline (89647.504 us; speedup 1.0000x reference)
//
#include <hip/hip_runtime.h>
#include <stdint.h>

#define NT 600

// ---- ws layout (bytes) ----
// XT  [600][3][64] f32      @ 0        (460800)
// H1  [2][400][64] f32      @ 460800   (204800)
// H2  [2][400][64] f32      @ 665600   (204800)
// H3  [2][400][64] f32      @ 870400   (204800)
// C1  [400][64] f32         @ 1075200  (102400)
// C2  [400][64] f32         @ 1177600  (102400)
// C3  [400][64] f32         @ 1280000  (102400)
// WIN [2][77][64] f32       @ 1382400  (39424)
// KAP [64][10] f32          @ 1421824  (2560)
// BC  [3][1600] f32         @ 1424384  (19200)   -> total 1443584 B
#define OFF_XT  0
#define OFF_H1  460800
#define OFF_H2  665600
#define OFF_H3  870400
#define OFF_C1  1075200
#define OFF_C2  1177600
#define OFF_C3  1280000
#define OFF_WIN 1382400
#define OFF_KAP 1421824
#define OFF_BC  1424384

struct Params {
  const float* x; const int* cs; const int* cl; const float* bias;
  const float *Wih1,*Whh1,*bih1,*bhh1,*Wih2,*Whh2,*bih2,*bhh2,*Wih3,*Whh3,*bih3,*bhh3;
  const float *Watt,*batt,*Wgmm,*bgmm;
  float *XT,*H1,*H2,*H3,*C1,*C2,*C3,*WIN,*KAP,*BC;
  float* out;
};

__device__ __forceinline__ float sigm(float x) { return 1.f / (1.f + expf(-x)); }

// dot over a concat segment: weights wr[0..n), source src[k][b] (stride-64 batch-major)
__device__ __forceinline__ float dotseg(const float* __restrict__ wr,
                                        const float* __restrict__ src,
                                        int n, int b) {
  float a0 = 0.f, a1 = 0.f, a2 = 0.f, a3 = 0.f;
  int k = 0;
  for (; k + 4 <= n; k += 4) {
    a0 += wr[k + 0] * src[(k + 0)*64 + b];
    a1 += wr[k + 1] * src[(k + 1)*64 + b];
    a2 += wr[k + 2] * src[(k + 2)*64 + b];
    a3 += wr[k + 3] * src[(k + 3)*64 + b];
  }
  for (; k < n; ++k) a0 += wr[k] * src[k*64 + b];
  return (a0 + a1) + (a2 + a3);
}

// =====================  prep: zero state, transpose x, combine biases  =====================
__global__ void prep_k(Params P) {
  const long long NXT = 600LL*3*64;            // 115200
  const long long NH  = 2LL*400*64;            // 51200 per layer
  const long long NC  = 400LL*64;              // 25600
  const long long NW  = 2LL*77*64;             // 9856
  const long long NK  = 640;
  const long long NBc = 4800;
  const long long TOT = NXT + 3*NH + 3*NC + NW + NK + NBc;
  const long long stride = (long long)gridDim.x * blockDim.x;
  for (long long idx = (long long)blockIdx.x*blockDim.x + threadIdx.x; idx < TOT; idx += stride) {
    long long i = idx;
    if (i < NXT) {
      int t = (int)(i / 192);
      int rem = (int)(i % 192);
      int k = rem / 64, b = rem % 64;
      P.XT[i] = P.x[((size_t)b*NT + t)*3 + k];
      continue;
    }
    i -= NXT;
    if (i < NH)  { P.H1[i] = 0.f; continue; }  i -= NH;
    if (i < NH)  { P.H2[i] = 0.f; continue; }  i -= NH;
    if (i < NH)  { P.H3[i] = 0.f; continue; }  i -= NH;
    if (i < NC)  { P.C1[i] = 0.f; continue; }  i -= NC;
    if (i < NC)  { P.C2[i] = 0.f; continue; }  i -= NC;
    if (i < NC)  { P.C3[i] = 0.f; continue; }  i -= NC;
    if (i < NW)  { P.WIN[i] = 0.f; continue; } i -= NW;
    if (i < NK)  { P.KAP[i] = 0.f; continue; } i -= NK;
    {
      int l = (int)(i / 1600), r = (int)(i % 1600);
      const float* bi = (l==0)?P.bih1:(l==1)?P.bih2:P.bih3;
      const float* bh = (l==0)?P.bhh1:(l==1)?P.bhh2:P.bhh3;
      P.BC[i] = bi[r] + bh[r];
    }
  }
}

// =====================  LSTM cell (one step): grid 200, block 256  =====================
// WG w owns h-dims {2w, 2w+1} for all 64 batches. Thread (b = tid&63, q = tid>>6) computes
// gate q. States are [dim][batch] (stride-64) for coalesced lane-b reads.
template<int L>
__global__ __launch_bounds__(256) void lstm_k(Params P, int t) {
  const int b = threadIdx.x & 63, q = threadIdx.x >> 6, w = blockIdx.x;
  const int cu = t & 1, pv = (t + 1) & 1;
  const float* Wih = (L==0) ? P.Wih1 : (L==1) ? P.Wih2 : P.Wih3;
  const float* Whh = (L==0) ? P.Whh1 : (L==1) ? P.Whh2 : P.Whh3;
  const int KIH = (L==0) ? 80 : (L==1) ? 480 : 880;
  float* hOwn = (L==0) ? P.H1 : (L==1) ? P.H2 : P.H3;
  float* cOwn = (L==0) ? P.C1 : (L==1) ? P.C2 : P.C3;
  __shared__ float gl[2][4][64];
  for (int dd = 0; dd < 2; ++dd) {
    int d = w*2 + dd, r = q*400 + d;          // gate rows: [i|f|g|o] blocks of 400
    const float* wih = Wih + (size_t)r*KIH;
    const float* whh = Whh + (size_t)r*400;
    float acc = P.BC[L*1600 + r];
    if (L == 0) {                              // concat([window_prev, x_t])
      acc += dotseg(wih,       P.WIN + pv*77*64, 77, b);
      acc += dotseg(wih + 77,  P.XT + t*192,      3, b);
    } else if (L == 1) {                       // concat([x_t, h1, window])
      acc += dotseg(wih,       P.XT + t*192,      3, b);
      acc += dotseg(wih + 3,   P.H1 + cu*25600, 400, b);
      acc += dotseg(wih + 403, P.WIN + cu*77*64, 77, b);
    } else {                                   // concat([x_t, h1, h2, window])
      acc += dotseg(wih,       P.XT + t*192,      3, b);
      acc += dotseg(wih + 3,   P.H1 + cu*25600, 400, b);
      acc += dotseg(wih + 403, P.H2 + cu*25600, 400, b);
      acc += dotseg(wih + 803, P.WIN + cu*77*64, 77, b);
    }
    acc += dotseg(whh, hOwn + pv*25600, 400, b);
    gl[dd][q][b] = acc;
  }
  __syncthreads();
  if (threadIdx.x < 128) {
    int dd = threadIdx.x >> 6, d = w*2 + dd;
    float gi = gl[dd][0][b], gf = gl[dd][1][b], gg = gl[dd][2][b], go = gl[dd][3][b];
    float c = sigm(gf)*cOwn[d*64 + b] + sigm(gi)*tanhf(gg);
    cOwn[d*64 + b] = c;
    hOwn[cu*25600 + d*64 + b] = sigm(go)*tanhf(c);
  }
}

// =====================  attention window (one step): grid 64 (=batch), block 64  =====================
__global__ __launch_bounds__(64) void att_k(Params P, int t) {
  const int b = blockIdx.x, tid = threadIdx.x, cu = t & 1;
  __shared__ float h1l[400], abk[30], kapl[10], phi[50], winl[77];
  for (int d = tid; d < 400; d += 64) h1l[d] = P.H1[cu*25600 + d*64 + b];
  for (int a = tid; a < 77; a += 64) winl[a] = 0.f;
  __syncthreads();
  if (tid < 30) {
    const float* wr = P.Watt + tid*400;
    float a0=0.f,a1=0.f,a2=0.f,a3=0.f;
    for (int d = 0; d < 400; d += 4) {
      a0 += wr[d+0]*h1l[d+0]; a1 += wr[d+1]*h1l[d+1];
      a2 += wr[d+2]*h1l[d+2]; a3 += wr[d+3]*h1l[d+3];
    }
    abk[tid] = expf((a0+a1)+(a2+a3) + P.batt[tid]);   // [alpha(10)|beta(10)|kstep(10)]
  }
  __syncthreads();
  if (tid < 10) {
    float kp = P.KAP[b*10 + tid] + abk[20 + tid];
    P.KAP[b*10 + tid] = kp;
    kapl[tid] = kp;
  }
  __syncthreads();
  if (tid < 50) {
    float s = 0.f;
    if (tid < P.cl[b]) {
      for (int k = 0; k < 10; ++k) {
        float dk = kapl[k] - (float)tid;
        s += abk[k]*expf(-abk[10 + k]*dk*dk);
      }
    }
    phi[tid] = s;
  }
  __syncthreads();
  if (tid == 0) {
    for (int u = 0; u < 50; ++u) winl[P.cs[b*50 + u]] += phi[u];
  }
  __syncthreads();
  for (int a = tid; a < 77; a += 64) P.WIN[cu*77*64 + a*64 + b] = winl[a];
}

// =====================  GMM head + epilogue (one step): grid 64 (=batch), block 128  =====================
__global__ __launch_bounds__(128) void gmm_k(Params P, int t) {
  const int b = blockIdx.x, tid = threadIdx.x, cu = t & 1;
  __shared__ float raw[121];
  __shared__ float sm[2];
  if (tid < 121) {
    const float* wr = P.Wgmm + (size_t)tid*1200;
    float acc = P.bgmm[tid];
    acc += dotseg(wr,       P.H1 + cu*25600, 400, b);
    acc += dotseg(wr + 400, P.H2 + cu*25600, 400, b);
    acc += dotseg(wr + 800, P.H3 + cu*25600, 400, b);
    raw[tid] = acc;
  }
  __syncthreads();
  const float bia = P.bias[b];
  if (tid == 0) {
    float m = -1e30f;
    for (int j = 1; j <= 20; ++j) m = fmaxf(m, raw[j]*(1.f + bia));
    float ss = 0.f;
    for (int j = 1; j <= 20; ++j) ss += expf(raw[j]*(1.f + bia) - m);
    sm[0] = m; sm[1] = ss;
  }
  __syncthreads();
  // y = [pis(20) | sigmas(40) | rhos(20) | mus(40) | es(1)]
  // out cols: e=0, pi=1..20, mu=21..60, sig=61..100, rho=101..120
  float* yr = P.out + ((size_t)b*NT + t)*121;
  if (tid == 0)           yr[120] = 1.f/(1.f + expf(-raw[0]));
  else if (tid <= 20)     yr[tid - 1] = expf(raw[tid]*(1.f + bia) - sm[0]) / sm[1];
  else if (tid <= 60)     yr[80 + tid - 21] = raw[tid];
  else if (tid <= 100)    yr[20 + tid - 61] = expf(raw[tid] - bia);
  else if (tid <= 120)    yr[60 + tid - 101] = tanhf(raw[tid]);
}

extern "C" void kernel_launch(void* const* d_in, const int* in_sizes, int n_in,
                              void* d_out, int out_size, void* d_ws, size_t ws_size,
                              hipStream_t stream) {
  (void)in_sizes; (void)n_in; (void)out_size; (void)ws_size;
  Params P;
  P.x    = (const float*)d_in[0];
  P.cs   = (const int*)d_in[1];
  P.cl   = (const int*)d_in[2];
  P.bias = (const float*)d_in[3];
  P.Wih1 = (const float*)d_in[4];  P.Whh1 = (const float*)d_in[5];
  P.bih1 = (const float*)d_in[6];  P.bhh1 = (const float*)d_in[7];
  P.Wih2 = (const float*)d_in[8];  P.Whh2 = (const float*)d_in[9];
  P.bih2 = (const float*)d_in[10]; P.bhh2 = (const float*)d_in[11];
  P.Wih3 = (const float*)d_in[12]; P.Whh3 = (const float*)d_in[13];
  P.bih3 = (const float*)d_in[14]; P.bhh3 = (const float*)d_in[15];
  P.Watt = (const float*)d_in[16]; P.batt = (const float*)d_in[17];
  P.Wgmm = (const float*)d_in[18]; P.bgmm = (const float*)d_in[19];
  char* ws = (char*)d_ws;
  P.XT  = (float*)(ws + OFF_XT);
  P.H1  = (float*)(ws + OFF_H1);
  P.H2  = (float*)(ws + OFF_H2);
  P.H3  = (float*)(ws + OFF_H3);
  P.C1  = (float*)(ws + OFF_C1);
  P.C2  = (float*)(ws + OFF_C2);
  P.C3  = (float*)(ws + OFF_C3);
  P.WIN = (float*)(ws + OFF_WIN);
  P.KAP = (float*)(ws + OFF_KAP);
  P.BC  = (float*)(ws + OFF_BC);
  P.out = (float*)d_out;

  hipLaunchKernelGGL(prep_k, dim3(512), dim3(256), 0, stream, P);
  for (int t = 0; t < NT; ++t) {
    hipLaunchKernelGGL((lstm_k<0>), dim3(200), dim3(256), 0, stream, P, t);
    hipLaunchKernelGGL(att_k,       dim3(64),  dim3(64),  0, stream, P, t);
    hipLaunchKernelGGL((lstm_k<1>), dim3(200), dim3(256), 0, stream, P, t);
    hipLaunchKernelGGL((lstm_k<2>), dim3(200), dim3(256), 0, stream, P, t);
    hipLaunchKernelGGL(gmm_k,       dim3(64),  dim3(128), 0, stream, P, t);
  }
}